// Round 6
// baseline (156.401 us; speedup 1.0000x reference)
//
#include <hip/hip_runtime.h>

// GruDirection2d forward_h: h[t] = z[t]*h_tilde[t] + (1-z[t])*h[t-1], scan over H.
// Shapes: z, h_tilde [B=4, C=64, H=512, W=512] f32; h0 [B, C, 1, W] f32. One
// thread per (b,c,w) chain.
//
// R1-R3: every source-level pipeline was collapsed by the compiler to ~2
// in-flight loads/lane (VGPR_Count=28) -> 1 MB chip-wide in flight -> 2.8 TB/s
// (Little's law), latency-bound. R4: segmentation w/o halo is wrong at segment
// starts. This version pins the pipeline at the ISA level: inline-asm
// global_load_dword with explicit "=v" destinations (cannot be deleted or
// re-coalesced), double-buffered 8-row blocks, counted s_waitcnt vmcnt(N)
// + sched_barrier(0) fences (rule #18). 16 loads/lane stay in flight during
// each compute+store phase -> ~8 MB in flight -> HBM-throughput-bound.
//
// vmcnt math (stores count!): steady queue at wait = [16 needed loads]
// [8 stores][16 newer loads] -> vmcnt(16); tail (no new loads) -> vmcnt(8).

constexpr int Bc = 4;
constexpr int Cc = 64;
constexpr int Hc = 512;
constexpr int Wc = 512;
constexpr int U  = 8;          // rows per pipeline block
constexpr int NB = Hc / U;     // 64 blocks
constexpr unsigned ROWB = Wc * sizeof(float);      // 2048 B between rows
constexpr unsigned BLKB = U * ROWB;                // 16384 B per block

#define FENCE() __builtin_amdgcn_sched_barrier(0)

// dst <- *(sbase + voff + imm)   (issued async; caller owns the waitcnt)
#define GLOAD(dst, voff, sbase, imm) \
    asm volatile("global_load_dword %0, %1, %2 offset:" #imm \
                 : "=v"(dst) : "v"(voff), "s"(sbase))

__global__ __launch_bounds__(256) void gru_h_scan(const float* __restrict__ z,
                                                  const float* __restrict__ ht,
                                                  const float* __restrict__ h0,
                                                  float* __restrict__ out) {
    const int cid = blockIdx.x * blockDim.x + threadIdx.x;  // [0, B*C*W)
    const int bc = cid >> 9;          // / Wc
    const int w  = cid & (Wc - 1);

    const size_t base = (size_t)bc * Hc * Wc + w;
    float* op = out + base;

    // h0 via asm too: keeps the compiler's waitcnt pass tracking ZERO loads,
    // so it never emits a pipeline-draining vmcnt(0) of its own.
    float h;
    {
        unsigned hoff = (unsigned)((bc * Wc + w) * sizeof(float));
        GLOAD(h, hoff, h0, 0);
        asm volatile("s_waitcnt vmcnt(0)");
        FENCE();
    }

    float zA[U], cA[U], zB[U], cB[U];
    unsigned voff = (unsigned)(base * sizeof(float));  // byte offset, row 0 of next load block

    // Issue all 16 loads of one block. Rows r=0..7 at voff + r*2048; imm covers
    // rows {0,1} per voffset reg (13-bit signed imm max 4095 < 2*2048).
    auto loadblk = [&](float (&zr)[U], float (&cr)[U], unsigned vo) {
        const unsigned v1 = vo + 2 * ROWB, v2 = vo + 4 * ROWB, v3 = vo + 6 * ROWB;
        GLOAD(zr[0], vo, z, 0);    GLOAD(zr[1], vo, z, 2048);
        GLOAD(zr[2], v1, z, 0);    GLOAD(zr[3], v1, z, 2048);
        GLOAD(zr[4], v2, z, 0);    GLOAD(zr[5], v2, z, 2048);
        GLOAD(zr[6], v3, z, 0);    GLOAD(zr[7], v3, z, 2048);
        GLOAD(cr[0], vo, ht, 0);   GLOAD(cr[1], vo, ht, 2048);
        GLOAD(cr[2], v1, ht, 0);   GLOAD(cr[3], v1, ht, 2048);
        GLOAD(cr[4], v2, ht, 0);   GLOAD(cr[5], v2, ht, 2048);
        GLOAD(cr[6], v3, ht, 0);   GLOAD(cr[7], v3, ht, 2048);
    };

    auto computeblk = [&](float (&zr)[U], float (&cr)[U], int blk) {
        const size_t roff = (size_t)blk * U * Wc;
#pragma unroll
        for (int i = 0; i < U; ++i) {
            h = fmaf(zr[i], cr[i], (1.0f - zr[i]) * h);
            op[roff + (size_t)i * Wc] = h;
        }
    };

    // Prologue: block 0 -> A
    loadblk(zA, cA, voff);
    voff += BLKB;
    FENCE();

#pragma unroll 1
    for (int b = 0; b < NB; b += 2) {
        // issue block b+1 -> B
        loadblk(zB, cB, voff);
        voff += BLKB;
        FENCE();
        asm volatile("s_waitcnt vmcnt(16)");   // A-loads retired (16 newest = B)
        FENCE();
        computeblk(zA, cA, b);
        FENCE();
        if (b + 2 < NB) {
            // issue block b+2 -> A
            loadblk(zA, cA, voff);
            voff += BLKB;
            FENCE();
            asm volatile("s_waitcnt vmcnt(16)");  // B retired (16 newest = A')
        } else {
            asm volatile("s_waitcnt vmcnt(8)");   // B retired (8 newest = stores)
        }
        FENCE();
        computeblk(zB, cB, b + 1);
        FENCE();
    }
}

extern "C" void kernel_launch(void* const* d_in, const int* in_sizes, int n_in,
                              void* d_out, int out_size, void* d_ws, size_t ws_size,
                              hipStream_t stream) {
    const float* z = (const float*)d_in[0];
    const float* h_tilde = (const float*)d_in[1];
    const float* h0 = (const float*)d_in[2];
    float* out = (float*)d_out;

    const int n_chains = Bc * Cc * Wc;      // 131072 scalar chains
    const int block = 256;
    const int grid = n_chains / block;      // 512 blocks -> 8 waves/CU
    gru_h_scan<<<grid, block, 0, stream>>>(z, h_tilde, h0, out);
}